// Round 1
// baseline (354.409 us; speedup 1.0000x reference)
//
#include <hip/hip_runtime.h>

#define CC 96
#define HH 128
#define WW 416
#define ND 49          // maxdisp+1 disparities
#define WT 208         // w-tile per block (W = 2*208)
#define HALO 48
#define CK 32          // channels per chunk (= MFMA K)
#define XST 40         // LDS row stride in halves (32 data + 8 pad)
#define OST 212        // epilogue LDS row stride in floats

typedef __attribute__((ext_vector_type(8))) short bf16x8;
typedef __attribute__((ext_vector_type(4))) float f32x4;

__device__ __forceinline__ unsigned short f2bf(float f) {
  unsigned int u = __float_as_uint(f);
  u += 0x7fffu + ((u >> 16) & 1u);   // round-to-nearest-even
  return (unsigned short)(u >> 16);
}

__device__ __forceinline__ void pack_row(const float4* v, int k, unsigned short* dst) {
  uint4 pk;
  pk.x = (unsigned)f2bf(((const float*)&v[0])[k]) | ((unsigned)f2bf(((const float*)&v[1])[k]) << 16);
  pk.y = (unsigned)f2bf(((const float*)&v[2])[k]) | ((unsigned)f2bf(((const float*)&v[3])[k]) << 16);
  pk.z = (unsigned)f2bf(((const float*)&v[4])[k]) | ((unsigned)f2bf(((const float*)&v[5])[k]) << 16);
  pk.w = (unsigned)f2bf(((const float*)&v[6])[k]) | ((unsigned)f2bf(((const float*)&v[7])[k]) << 16);
  *(uint4*)dst = pk;
}

__global__ __launch_bounds__(256, 3)
void costvol_kernel(const float* __restrict__ x, const float* __restrict__ y,
                    float* __restrict__ out) {
  // LDS union: phase 1/2: XT bf16[208][40] @0, YT bf16[256][40] @8320 halves (37120 B)
  //            phase 3  : OL f32[49][212] (41552 B)
  __shared__ __align__(16) unsigned short smem[20776];   // 41552 bytes
  unsigned short* XT = smem;
  unsigned short* YT = smem + WT * XST;
  float* OL = (float*)smem;

  const int tid  = threadIdx.x;
  const int lane = tid & 63;
  const int wave = tid >> 6;
  const int m    = lane & 15;            // MFMA row (A) / col (B,D)
  const int hi   = lane >> 4;            // MFMA k-octet selector
  const int rcol = ((hi ^ (m >> 2)) & 3) * 8;  // swizzled k-octet offset

  const int bid  = blockIdx.x;
  const int half = bid & 1;
  const int h    = (bid >> 1) & (HH - 1);
  const int b    = bid >> 8;
  const int w0   = half * WT;
  const int j0   = w0 - HALO;

  f32x4 acc[4][4];
#pragma unroll
  for (int r = 0; r < 4; ++r)
#pragma unroll
    for (int n = 0; n < 4; ++n)
      acc[r][n] = (f32x4){0.f, 0.f, 0.f, 0.f};

  for (int ch = 0; ch < 3; ++ch) {
    const int c0 = ch * CK;

    // ---- stage Y tile: 256 threads = 4 c-octets x 64 j-groups of 4
    {
      const int o  = wave;
      const int g  = lane;
      const int jj = g * 4;
      const int jg = j0 + jj;            // absolute j (multiple of 4; all-neg or all-valid)
      float4 v[8];
      if (jg >= 0) {
        const float* py = y + ((size_t)(b * CC + c0 + o * 8) * HH + h) * WW + jg;
#pragma unroll
        for (int i = 0; i < 8; ++i)
          v[i] = *(const float4*)(py + (size_t)i * HH * WW);
      } else {
#pragma unroll
        for (int i = 0; i < 8; ++i)
          v[i] = make_float4(0.f, 0.f, 0.f, 0.f);   // zero halo -> zero outputs where w-d<0
      }
      const int co = ((o ^ (g & 3)) & 3) * 8;
#pragma unroll
      for (int k = 0; k < 4; ++k)
        pack_row(v, k, &YT[(jj + k) * XST + co]);
    }

    // ---- stage X tile: first 208 threads = 4 c-octets x 52 w-groups of 4
    if (tid < 208) {
      const int o  = tid / 52;
      const int g  = tid - o * 52;
      const int wg = g * 4;
      const float* px = x + ((size_t)(b * CC + c0 + o * 8) * HH + h) * WW + w0 + wg;
      float4 v[8];
#pragma unroll
      for (int i = 0; i < 8; ++i)
        v[i] = *(const float4*)(px + (size_t)i * HH * WW);
      const int co = ((o ^ (g & 3)) & 3) * 8;
#pragma unroll
      for (int k = 0; k < 4; ++k)
        pack_row(v, k, &XT[(wg + k) * XST + co]);
    }
    __syncthreads();

    // ---- banded MFMA: wave handles m-tiles {wave, wave+4, wave+8, wave+12}
#pragma unroll
    for (int r = 0; r < 4; ++r) {
      const int mt = wave + r * 4;
      if (mt < 13) {
        bf16x8 av = *(const bf16x8*)&XT[(mt * 16 + m) * XST + rcol];
#pragma unroll
        for (int nt = 0; nt < 4; ++nt) {
          bf16x8 bv = *(const bf16x8*)&YT[((mt + nt) * 16 + m) * XST + rcol];
          acc[r][nt] = __builtin_amdgcn_mfma_f32_16x16x32_bf16(av, bv, acc[r][nt], 0, 0, 0);
        }
      }
    }
    __syncthreads();
  }

  // ---- epilogue: diagonal remap acc -> OL[d][w_local]
#pragma unroll
  for (int r = 0; r < 4; ++r) {
    const int mt = wave + r * 4;
    if (mt < 13) {
#pragma unroll
      for (int nt = 0; nt < 4; ++nt) {
#pragma unroll
        for (int i = 0; i < 4; ++i) {
          const int ml = hi * 4 + i;               // row within m-tile (w)
          const int d  = HALO + ml - nt * 16 - m;  // disparity = w - j
          if (d >= 0 && d < ND)
            OL[d * OST + mt * 16 + ml] = acc[r][nt][i];
        }
      }
    }
  }
  __syncthreads();

  // ---- coalesced float4 stores: 49 rows x 52 float4
  const size_t ob = ((size_t)(b * ND) * HH + h) * WW + w0;
  for (int t = tid; t < ND * 52; t += 256) {
    const int d = t / 52;
    const int g = t - d * 52;
    float4 v = *(const float4*)&OL[d * OST + g * 4];
    *(float4*)&out[ob + (size_t)d * HH * WW + g * 4] = v;
  }
}

extern "C" void kernel_launch(void* const* d_in, const int* in_sizes, int n_in,
                              void* d_out, int out_size, void* d_ws, size_t ws_size,
                              hipStream_t stream) {
  (void)in_sizes; (void)n_in; (void)d_ws; (void)ws_size; (void)out_size;
  const float* x = (const float*)d_in[0];
  const float* y = (const float*)d_in[1];
  float* out = (float*)d_out;
  dim3 grid(8 * HH * 2);   // b * h * w-half = 2048 blocks
  dim3 block(256);
  hipLaunchKernelGGL(costvol_kernel, grid, block, 0, stream, x, y, out);
}